// Round 12
// baseline (220.388 us; speedup 1.0000x reference)
//
#include <hip/hip_runtime.h>

#define BATCH   2
#define SEQ     2048
#define DMODEL  1024
#define NHEADS  16
#define DHEAD   64
#define NGROUPS 8
#define NTOK    (BATCH * SEQ)   // 4096
#define QKV_N   2048            // 1024 Q | 512 K | 512 V

typedef unsigned short ushort_t;
typedef unsigned int u32;
typedef __attribute__((ext_vector_type(8))) short short8;
typedef __attribute__((ext_vector_type(4))) float f32x4;
typedef __attribute__((ext_vector_type(16))) float f32x16;

#define MFMA16(a, b, c) __builtin_amdgcn_mfma_f32_16x16x32_bf16((a), (b), (c), 0, 0, 0)
#define MFMA32(a, b, c) __builtin_amdgcn_mfma_f32_32x32x16_bf16((a), (b), (c), 0, 0, 0)

// async global->LDS, 16B per lane, LDS dest = wave-uniform base + lane*16
#define GLOAD16(gp, lp)                                                        \
    __builtin_amdgcn_global_load_lds(                                          \
        (const u32 __attribute__((address_space(1)))*)(gp),                    \
        (u32 __attribute__((address_space(3)))*)(lp), 16, 0, 0)

// pack 2 f32 -> 1 u32 of 2 bf16 (RNE), elem0 = lo
#define CVTPK(dst, lo, hi) \
    asm("v_cvt_pk_bf16_f32 %0, %1, %2" : "=v"(dst) : "v"(lo), "v"(hi))

// a' = [a.lo | b.lo-of-partner], b' = [a.hi-of-partner | b.hi]
#define PLSWAP(a, b) \
    asm("v_permlane32_swap_b32 %0, %1" : "+v"(a), "+v"(b))

__device__ __forceinline__ ushort_t f2bu(float x) {
    unsigned u = __builtin_bit_cast(unsigned, x);
    unsigned r = (u + 0x7fffu + ((u >> 16) & 1u)) >> 16;   // RNE
    return (ushort_t)r;
}

// ---------------------------------------------------------------------------
// Fused prep: cvt_resid (blocks 0..4095) | tr_wqkv (4096..4607) |
//             tr_wout (4608..4863).  Whole-block branch, no divergence.
// ---------------------------------------------------------------------------
__global__ __launch_bounds__(256) void prep(
    const float* __restrict__ resid,
    const float* __restrict__ Wq, const float* __restrict__ Wk,
    const float* __restrict__ Wv, const float* __restrict__ Wout,
    ushort_t* __restrict__ rbf, ushort_t* __restrict__ Wt,
    ushort_t* __restrict__ Wot)
{
    __shared__ float Ws[64][65];
    const int t = threadIdx.x;
    const int bid = blockIdx.x;

    if (bid < 4096) {
        const int i4 = bid * 256 + t;
        union { float4 v; float f[4]; } a;
        a.v = *reinterpret_cast<const float4*>(resid + (size_t)i4 * 4);
        union { uint2 v; ushort_t u[4]; } o;
        #pragma unroll
        for (int j = 0; j < 4; ++j) o.u[j] = f2bu(a.f[j]);
        *reinterpret_cast<uint2*>(rbf + (size_t)i4 * 4) = o.v;
        return;
    }

    if (bid < 4096 + 512) {
        const int rel = bid - 4096;
        const int k0 = (rel & 15) * 64;
        const int n0 = (rel >> 4) * 64;

        const float* src; int stride, boff;
        if (n0 < 1024)       { src = Wq; stride = 1024; boff = n0; }
        else if (n0 < 1536)  { src = Wk; stride = 512;  boff = n0 - 1024; }
        else                 { src = Wv; stride = 512;  boff = n0 - 1536; }

        #pragma unroll
        for (int i = 0; i < 4; ++i) {
            const int c = i * 256 + t;
            const int row = c >> 4, cc = (c & 15) * 4;
            union { float4 v; float f[4]; } a;
            a.v = *reinterpret_cast<const float4*>(
                src + (size_t)(k0 + row) * stride + boff + cc);
            #pragma unroll
            for (int j = 0; j < 4; ++j) Ws[row][cc + j] = a.f[j];
        }
        __syncthreads();
        #pragma unroll
        for (int i = 0; i < 2; ++i) {
            const int c = i * 256 + t;
            const int nr = c >> 3, kc = (c & 7) * 8;
            union { uint4 v; ushort_t u[8]; } o;
            #pragma unroll
            for (int j = 0; j < 8; ++j) o.u[j] = f2bu(Ws[kc + j][nr]);
            *reinterpret_cast<uint4*>(Wt + (size_t)(n0 + nr) * 1024 + k0 + kc) = o.v;
        }
        return;
    }

    {
        const int rel = bid - 4608;
        const int d0 = (rel & 15) * 64;
        const int h  = rel >> 4;

        #pragma unroll
        for (int i = 0; i < 4; ++i) {
            const int c = i * 256 + t;
            const int e = c >> 4, dd = (c & 15) * 4;
            union { float4 v; float f[4]; } a;
            a.v = *reinterpret_cast<const float4*>(
                Wout + (size_t)(e * 16 + h) * 1024 + d0 + dd);
            #pragma unroll
            for (int j = 0; j < 4; ++j) Ws[e][dd + j] = a.f[j];
        }
        __syncthreads();
        #pragma unroll
        for (int i = 0; i < 2; ++i) {
            const int c = i * 256 + t;
            const int dr = c >> 3, ec = (c & 7) * 8;
            union { uint4 v; ushort_t u[8]; } o;
            #pragma unroll
            for (int j = 0; j < 8; ++j) o.u[j] = f2bu(Ws[ec + j][dr]);
            *reinterpret_cast<uint4*>(Wot + (size_t)(d0 + dr) * 1024 + h * 64 + ec) = o.v;
        }
    }
}

// ---------------------------------------------------------------------------
// Prep (after qkv_gemm): Vt[b][g][e][s] bf16 from qkv V slab.
// ---------------------------------------------------------------------------
__global__ __launch_bounds__(256) void tr_v(
    const ushort_t* __restrict__ qkv, ushort_t* __restrict__ Vt)
{
    __shared__ ushort_t T[64][72];
    const int t  = threadIdx.x;
    const int s0 = blockIdx.x * 64;
    const int g  = blockIdx.y;
    const int b  = blockIdx.z;

    #pragma unroll
    for (int i = 0; i < 2; ++i) {
        const int c = i * 256 + t;
        const int row = c >> 3, ec = (c & 7) * 8;
        *reinterpret_cast<uint4*>(&T[row][ec]) =
            *reinterpret_cast<const uint4*>(
                qkv + (size_t)(b * SEQ + s0 + row) * QKV_N + 1536 + g * 64 + ec);
    }
    __syncthreads();
    #pragma unroll
    for (int i = 0; i < 2; ++i) {
        const int c = i * 256 + t;
        const int er = c >> 3, sc = (c & 7) * 8;
        union { uint4 v; ushort_t u[8]; } o;
        #pragma unroll
        for (int j = 0; j < 8; ++j) o.u[j] = T[sc + j][er];
        *reinterpret_cast<uint4*>(
            Vt + (size_t)((b * NGROUPS + g) * 64 + er) * SEQ + s0 + sc) = o.v;
    }
}

// ---------------------------------------------------------------------------
// qkv_gemm v6: R10 structure + bijective XCD swizzle (T1): hardware-linear
// id d -> logical (d%8)*64 + d/8, so XCD k owns 4 contiguous M-panels x all
// of B (4MB B + 1MB A ~ L2-resident per XCD).
// ---------------------------------------------------------------------------
__global__ __launch_bounds__(512) void qkv_gemm(
    const ushort_t* __restrict__ A, const ushort_t* __restrict__ Bt,
    ushort_t* __restrict__ C)
{
    __shared__ ushort_t As[2][128][64];
    __shared__ ushort_t Bs[2][128][64];

    const int t = threadIdx.x;
    const int wave = t >> 6, lane = t & 63;
    const int quad = lane >> 4, x = lane & 15;
    const int wm = (wave >> 1) * 32, wn = (wave & 1) * 64;

    const int lin = blockIdx.x + 16 * blockIdx.y;       // 0..511
    const int swz = ((lin & 7) << 6) | (lin >> 3);      // bijective on 512
    const int m0 = (swz >> 4) * 128, n0 = (swz & 15) * 128;

    const int sr8 = lane >> 3;          // row within an 8-row gload group
    const int gc  = (lane & 7) ^ sr8;   // swizzled source chunk

    f32x4 acc[2][4];
    #pragma unroll
    for (int i = 0; i < 2; ++i)
        #pragma unroll
        for (int j = 0; j < 4; ++j) acc[i][j] = (f32x4)(0.f);

    // prologue: stage k0=0 into buf0
    #pragma unroll
    for (int s = 0; s < 2; ++s) {
        const int r0 = (wave * 2 + s) * 8;
        GLOAD16(A  + (size_t)(m0 + r0 + sr8) * 1024 + gc * 8, &As[0][r0][0]);
        GLOAD16(Bt + (size_t)(n0 + r0 + sr8) * 1024 + gc * 8, &Bs[0][r0][0]);
    }
    __syncthreads();

    int cur = 0;
    for (int k0 = 0; k0 < 1024; k0 += 64) {
        if (k0 + 64 < 1024) {           // issue next-tile loads (fly during MFMA)
            #pragma unroll
            for (int s = 0; s < 2; ++s) {
                const int r0 = (wave * 2 + s) * 8;
                GLOAD16(A  + (size_t)(m0 + r0 + sr8) * 1024 + k0 + 64 + gc * 8,
                        &As[cur ^ 1][r0][0]);
                GLOAD16(Bt + (size_t)(n0 + r0 + sr8) * 1024 + k0 + 64 + gc * 8,
                        &Bs[cur ^ 1][r0][0]);
            }
        }
        #pragma unroll
        for (int j = 0; j < 2; ++j) {
            const int cs = ((j * 4 + quad) ^ (x & 7)) * 8;
            short8 af[2], bf[4];
            #pragma unroll
            for (int mt = 0; mt < 2; ++mt)
                af[mt] = *reinterpret_cast<const short8*>(&As[cur][wm + mt * 16 + x][cs]);
            #pragma unroll
            for (int nt = 0; nt < 4; ++nt)
                bf[nt] = *reinterpret_cast<const short8*>(&Bs[cur][wn + nt * 16 + x][cs]);
            #pragma unroll
            for (int mt = 0; mt < 2; ++mt)
                #pragma unroll
                for (int nt = 0; nt < 4; ++nt)
                    acc[mt][nt] = MFMA16(af[mt], bf[nt], acc[mt][nt]);
        }
        __syncthreads();                // drains vmcnt -> next buf complete
        cur ^= 1;
    }

    #pragma unroll
    for (int mt = 0; mt < 2; ++mt)
        #pragma unroll
        for (int nt = 0; nt < 4; ++nt)
            #pragma unroll
            for (int r = 0; r < 4; ++r) {
                const int row = m0 + wm + mt * 16 + quad * 4 + r;
                const int col = n0 + wn + nt * 16 + x;
                C[(size_t)row * QKV_N + col] = f2bu(acc[mt][nt][r]);
            }
}

// ---------------------------------------------------------------------------
// out_gemm v6: R10 structure + the same XCD swizzle (3MB/XCD working set).
// ---------------------------------------------------------------------------
__global__ __launch_bounds__(512) void out_gemm(
    const ushort_t* __restrict__ A, const ushort_t* __restrict__ Bt,
    const float* __restrict__ bias, float* __restrict__ C)
{
    __shared__ ushort_t As[2][128][64];
    __shared__ ushort_t Bs[2][64][64];

    const int t = threadIdx.x;
    const int wave = t >> 6, lane = t & 63;
    const int quad = lane >> 4, x = lane & 15;
    const int wm = (wave >> 1) * 32, wn = (wave & 1) * 32;

    const int lin = blockIdx.x + 16 * blockIdx.y;       // 0..511
    const int swz = ((lin & 7) << 6) | (lin >> 3);      // bijective on 512
    const int m0 = (swz >> 4) * 128, n0 = (swz & 15) * 64;

    const int sr8 = lane >> 3;
    const int gc  = (lane & 7) ^ sr8;

    f32x4 acc[2][2];
    #pragma unroll
    for (int i = 0; i < 2; ++i)
        #pragma unroll
        for (int j = 0; j < 2; ++j) acc[i][j] = (f32x4)(0.f);

    // prologue: stage k0=0 into buf0
    #pragma unroll
    for (int s = 0; s < 2; ++s) {
        const int r0 = (wave * 2 + s) * 8;
        GLOAD16(A + (size_t)(m0 + r0 + sr8) * 1024 + gc * 8, &As[0][r0][0]);
    }
    {
        const int r0 = wave * 8;
        GLOAD16(Bt + (size_t)(n0 + r0 + sr8) * 1024 + gc * 8, &Bs[0][r0][0]);
    }
    __syncthreads();

    int cur = 0;
    for (int k0 = 0; k0 < 1024; k0 += 64) {
        if (k0 + 64 < 1024) {
            #pragma unroll
            for (int s = 0; s < 2; ++s) {
                const int r0 = (wave * 2 + s) * 8;
                GLOAD16(A + (size_t)(m0 + r0 + sr8) * 1024 + k0 + 64 + gc * 8,
                        &As[cur ^ 1][r0][0]);
            }
            const int r0 = wave * 8;
            GLOAD16(Bt + (size_t)(n0 + r0 + sr8) * 1024 + k0 + 64 + gc * 8,
                    &Bs[cur ^ 1][r0][0]);
        }
        #pragma unroll
        for (int j = 0; j < 2; ++j) {
            const int cs = ((j * 4 + quad) ^ (x & 7)) * 8;
            short8 af[2], bf[2];
            #pragma unroll
            for (int mt = 0; mt < 2; ++mt)
                af[mt] = *reinterpret_cast<const short8*>(&As[cur][wm + mt * 16 + x][cs]);
            #pragma unroll
            for (int nt = 0; nt < 2; ++nt)
                bf[nt] = *reinterpret_cast<const short8*>(&Bs[cur][wn + nt * 16 + x][cs]);
            #pragma unroll
            for (int mt = 0; mt < 2; ++mt)
                #pragma unroll
                for (int nt = 0; nt < 2; ++nt)
                    acc[mt][nt] = MFMA16(af[mt], bf[nt], acc[mt][nt]);
        }
        __syncthreads();
        cur ^= 1;
    }

    float bv[2];
    #pragma unroll
    for (int nt = 0; nt < 2; ++nt) bv[nt] = bias[n0 + wn + nt * 16 + x];

    #pragma unroll
    for (int mt = 0; mt < 2; ++mt)
        #pragma unroll
        for (int nt = 0; nt < 2; ++nt)
            #pragma unroll
            for (int r = 0; r < 4; ++r) {
                const int row = m0 + wm + mt * 16 + quad * 4 + r;
                const int col = n0 + wn + nt * 16 + x;
                C[(size_t)row * 1024 + col] = acc[mt][nt][r] + bv[nt];
            }
}

// ---------------------------------------------------------------------------
// MFMA flash attention, v14 — v13 (CORRECT, barrier-free) + the pipeline
// v13 was missing:
//  - K fragments REGISTER double-buffered: kt+1's 4 frags issued while kt
//    computes (v10's hiding distance, without barriers/LDS).
//  - V fragments issued at iter top, consumed ~250cy later (after 4 chained
//    QK MFMAs + 16 exp + pack) -> L2 latency covered.
//  - unrolled-by-2 with NAMED A/B frag sets (no runtime-indexed locals).
//  - per-wave live-iter bound nkt_w (live set is a kt-prefix == v13's skip).
//  - combine tree / masks / z-write byte-identical to v13 (passed).
// ---------------------------------------------------------------------------
#define LOADK(KT, DST)                                                        \
    {                                                                         \
        const int cb_ = (KT) * 128 + kw * 32;                                 \
        _Pragma("unroll")                                                     \
        for (int sl = 0; sl < 4; ++sl)                                        \
            DST[sl] = *reinterpret_cast<const short8*>(                       \
                kg + (size_t)(cb_ + x31) * QKV_N + sl * 16 + hi * 8);         \
    }

#define ATTN_ITER(KT, KF, KNEXT)                                              \
    {                                                                         \
        const int kt_ = (KT);                                                 \
        const int cbase_ = kt_ * 128 + kw * 32;                               \
        const bool full_ = (cbase_ + 31 <= qmin);                             \
        /* V frags: issue now, consume after softmax */                       \
        short8 vf0_[2], vf1_[2];                                              \
        _Pragma("unroll")                                                     \
        for (int ks = 0; ks < 2; ++ks) {                                      \
            const size_t vcol_ =                                              \
                (size_t)(kt_ * 128 + (kw * 4 + ks * 2 + hi) * 8);             \
            vf0_[ks] = *reinterpret_cast<const short8*>(                      \
                vg + (size_t)x31 * SEQ + vcol_);                              \
            vf1_[ks] = *reinterpret_cast<const short8*>(                      \
                vg + (size_t)(32 + x31) * SEQ + vcol_);                       \
        }                                                                     \
        /* prefetch next iter's K frags */                                    \
        if (kt_ + 1 < nkt_w) LOADK(kt_ + 1, KNEXT);                           \
        /* S^T = K . Q^T */                                                   \
        f32x16 st = (f32x16)(0.f);                                            \
        __builtin_amdgcn_s_setprio(1);                                        \
        _Pragma("unroll")                                                     \
        for (int sl = 0; sl < 4; ++sl) st = MFMA32(KF[sl], aq[sl], st);       \
        __builtin_amdgcn_s_setprio(0);                                        \
        /* p = exp(s/8) + mask */                                             \
        const int ql_ = qmin + x31 - cbase_;                                  \
        float p[16];                                                          \
        float s16 = 0.f;                                                      \
        _Pragma("unroll")                                                     \
        for (int r = 0; r < 16; ++r) {                                        \
            const int keyoff = (r & 3) + 8 * (r >> 2);                        \
            float pv = __expf(st[r] * 0.125f);                                \
            if (!full_) pv = (keyoff + 4 * hi > ql_) ? 0.f : pv;              \
            p[r] = pv;                                                        \
            s16 += pv;                                                        \
        }                                                                     \
        lown += s16;                                                          \
        /* pack + permlane into PV B-frags */                                 \
        u32 pk0, pk1, pk2, pk3, pk4, pk5, pk6, pk7;                           \
        CVTPK(pk0, p[0],  p[1]);  CVTPK(pk1, p[2],  p[3]);                    \
        CVTPK(pk2, p[4],  p[5]);  CVTPK(pk3, p[6],  p[7]);                    \
        CVTPK(pk4, p[8],  p[9]);  CVTPK(pk5, p[10], p[11]);                   \
        CVTPK(pk6, p[12], p[13]); CVTPK(pk7, p[14], p[15]);                   \
        PLSWAP(pk0, pk2); PLSWAP(pk1, pk3);                                   \
        PLSWAP(pk4, pk6); PLSWAP(pk5, pk7);                                   \
        union { u32 u[4]; short8 s; } f0, f1;                                 \
        f0.u[0] = pk0; f0.u[1] = pk1; f0.u[2] = pk2; f0.u[3] = pk3;           \
        f1.u[0] = pk4; f1.u[1] = pk5; f1.u[2] = pk6; f1.u[3] = pk7;           \
        /* O^T += V^T . P^T */                                                \
        __builtin_amdgcn_s_setprio(1);                                        \
        o0 = MFMA32(vf0_[0], f0.s, o0);                                       \
        o1 = MFMA32(vf1_[0], f0.s, o1);                                       \
        o0 = MFMA32(vf0_[1], f1.s, o0);                                       \
        o1 = MFMA32(vf1_[1], f1.s, o1);                                       \
        __builtin_amdgcn_s_setprio(0);                                        \
    }

__global__ __launch_bounds__(512, 4) void attn(
    const ushort_t* __restrict__ qkv, const ushort_t* __restrict__ Vt,
    ushort_t* __restrict__ z)
{
    __shared__ float Ob1[64 * 64];    // [64e][64q]
    __shared__ float Ob3[64 * 64];
    __shared__ float Ofin[64 * 64];
    __shared__ float Lb1[64];
    __shared__ float Lb3[64];

    const int t = threadIdx.x;
    const int wave = t >> 6, lane = t & 63;
    const int x31 = lane & 31, hi = lane >> 5;
    const int rw = wave & 1;          // q 32-row half of the 64-row tile
    const int kw = wave >> 1;         // 32-key chunk of the 128-key tile

    const int h  = blockIdx.x;
    const int qp = blockIdx.y;
    const int b  = blockIdx.z;
    const int g  = h >> 1;

    const ushort_t* kg = qkv + (size_t)(b * SEQ) * QKV_N + 1024 + g * 64;
    const ushort_t* vg = Vt + (size_t)((b * NGROUPS + g) * 64) * SEQ;

    const int qloc = rw * 32 + x31;

    #pragma unroll
    for (int phase = 0; phase < 2; ++phase) {
        const int qt = phase ? (31 - qp) : qp;
        const int qrow0 = qt * 64;
        const int nkt = (qt >> 1) + 1;
        const int qmin = qrow0 + rw * 32;

        // per-wave live-iteration count (live set is a prefix of kt)
        int nkt_w;
        {
            const int d = qmin + 31 - kw * 32;
            nkt_w = (d < 0) ? 0 : (d / 128) + 1;
            if (nkt_w > nkt) nkt_w = nkt;
        }

        // ---- Q fragments (B-frag: lane holds Q[qloc][sl*16+hi*8 ..+7]) ----
        short8 aq[4];
        #pragma unroll
        for (int sl = 0; sl < 4; ++sl)
            aq[sl] = *reinterpret_cast<const short8*>(
                qkv + (size_t)(b * SEQ + qrow0 + qloc) * QKV_N + h * 64 + sl * 16 + hi * 8);

        f32x16 o0 = (f32x16)(0.f), o1 = (f32x16)(0.f);
        float lown = 0.f;

        short8 kA[4], kB[4];
        if (nkt_w > 0) {
            LOADK(0, kA);
            for (int kt2 = 0; kt2 < nkt_w; kt2 += 2) {
                ATTN_ITER(kt2, kA, kB);
                if (kt2 + 1 < nkt_w) ATTN_ITER(kt2 + 1, kB, kA);
            }
        }

        // ---- l: partner-exchange (lanes l <-> l+32 hold same q) ----
        float ltot;
        {
            u32 la = __builtin_bit_cast(u32, lown), lb = la;
            PLSWAP(la, lb);
            const float lpart = __builtin_bit_cast(float, hi ? la : lb);
            ltot = lown + lpart;
        }

        // ---- combine kw partials (tree via LDS; v13-verified) ----
        if (kw == 1 || kw == 3) {
            float* Obx = (kw == 1) ? Ob1 : Ob3;
            float* Lbx = (kw == 1) ? Lb1 : Lb3;
            #pragma unroll
            for (int r = 0; r < 16; ++r) {
                const int e = (r & 3) + 8 * (r >> 2) + 4 * hi;
                Obx[e * 64 + qloc]        = o0[r];
                Obx[(32 + e) * 64 + qloc] = o1[r];
            }
            if (hi == 0) Lbx[qloc] = ltot;
        }
        __syncthreads();
        if (kw == 0 || kw == 2) {
            const float* Obx = (kw == 0) ? Ob1 : Ob3;
            const float* Lbx = (kw == 0) ? Lb1 : Lb3;
            #pragma unroll
            for (int r = 0; r < 16; ++r) {
                const int e = (r & 3) + 8 * (r >> 2) + 4 * hi;
                o0[r] += Obx[e * 64 + qloc];
                o1[r] += Obx[(32 + e) * 64 + qloc];
            }
            ltot += Lbx[qloc];
        }
        __syncthreads();
        if (kw == 2) {
            #pragma unroll
            for (int r = 0; r < 16; ++r) {
                const int e = (r & 3) + 8 * (r >> 2) + 4 * hi;
                Ob1[e * 64 + qloc]        = o0[r];
                Ob1[(32 + e) * 64 + qloc] = o1[r];
            }
            if (hi == 0) Lb1[qloc] = ltot;
        }
        __syncthreads();
        if (kw == 0) {
            #pragma unroll
            for (int r = 0; r < 16; ++r) {
                const int e = (r & 3) + 8 * (r >> 2) + 4 * hi;
                o0[r] += Ob1[e * 64 + qloc];
                o1[r] += Ob1[(32 + e) * 64 + qloc];
            }
            ltot += Lb1[qloc];
            const float inv = 1.f / ltot;
            #pragma unroll
            for (int r = 0; r < 16; ++r) {
                const int e = (r & 3) + 8 * (r >> 2) + 4 * hi;
                Ofin[e * 64 + qloc]        = o0[r] * inv;
                Ofin[(32 + e) * 64 + qloc] = o1[r] * inv;
            }
        }
        __syncthreads();

        // ---- z-write: coalesced 16B stores via LDS transpose ----
        {
            const int q = t >> 3, ec = t & 7;
            union { u32 u[4]; uint4 v; } pkz;
            #pragma unroll
            for (int j2 = 0; j2 < 4; ++j2) {
                float v0 = Ofin[(ec * 8 + 2 * j2) * 64 + q];
                float v1 = Ofin[(ec * 8 + 2 * j2 + 1) * 64 + q];
                CVTPK(pkz.u[j2], v0, v1);
            }
            *reinterpret_cast<uint4*>(
                z + (size_t)(b * SEQ + qrow0 + q) * 1024 + h * 64 + ec * 8) = pkz.v;
        }
        __syncthreads();   // Ofin reads done before next phase's combine writes
    }
}

// ---------------------------------------------------------------------------
extern "C" void kernel_launch(void* const* d_in, const int* in_sizes, int n_in,
                              void* d_out, int out_size, void* d_ws, size_t ws_size,
                              hipStream_t stream)
{
    const float* resid = (const float*)d_in[0];
    const float* Wq    = (const float*)d_in[1];
    const float* Wk    = (const float*)d_in[2];
    const float* Wv    = (const float*)d_in[3];
    const float* Wout  = (const float*)d_in[4];
    const float* bout  = (const float*)d_in[5];
    float* out = (float*)d_out;

    ushort_t* rbf   = (ushort_t*)d_ws;                       //  8 MB  [4096][1024]
    ushort_t* wqkvt = rbf   + (size_t)NTOK * DMODEL;         //  4 MB  [2048][1024]
    ushort_t* woutt = wqkvt + (size_t)QKV_N * DMODEL;        //  2 MB  [1024][1024]
    ushort_t* qkv   = woutt + (size_t)DMODEL * DMODEL;       // 16 MB  [4096][2048]
    ushort_t* z     = qkv   + (size_t)NTOK * QKV_N;          //  8 MB  [4096][1024]
    ushort_t* vt    = rbf;   // alias: rbf dead after qkv_gemm; tr_v runs later

    prep     <<<dim3(4864), 256, 0, stream>>>(resid, Wq, Wk, Wv, Wout,
                                              rbf, wqkvt, woutt);
    qkv_gemm <<<dim3(16, 32), 512, 0, stream>>>(rbf, wqkvt, qkv);
    tr_v     <<<dim3(SEQ / 64, NGROUPS, BATCH), 256, 0, stream>>>(qkv, vt);
    attn     <<<dim3(16, 16, 2), 512, 0, stream>>>(qkv, vt, z);
    out_gemm <<<dim3(16, 32), 512, 0, stream>>>(z, woutt, bout, out);
}

// Round 13
// 164.337 us; speedup vs baseline: 1.3411x; 1.3411x over previous
//
#include <hip/hip_runtime.h>

#define BATCH   2
#define SEQ     2048
#define DMODEL  1024
#define NHEADS  16
#define DHEAD   64
#define NGROUPS 8
#define NTOK    (BATCH * SEQ)   // 4096
#define QKV_N   2048            // 1024 Q | 512 K | 512 V

typedef unsigned short ushort_t;
typedef unsigned int u32;
typedef __attribute__((ext_vector_type(8))) short short8;
typedef __attribute__((ext_vector_type(4))) float f32x4;
typedef __attribute__((ext_vector_type(16))) float f32x16;

#define MFMA16(a, b, c) __builtin_amdgcn_mfma_f32_16x16x32_bf16((a), (b), (c), 0, 0, 0)
#define MFMA32(a, b, c) __builtin_amdgcn_mfma_f32_32x32x16_bf16((a), (b), (c), 0, 0, 0)

// async global->LDS, 16B per lane, LDS dest = wave-uniform base + lane*16
#define GLOAD16(gp, lp)                                                        \
    __builtin_amdgcn_global_load_lds(                                          \
        (const u32 __attribute__((address_space(1)))*)(gp),                    \
        (u32 __attribute__((address_space(3)))*)(lp), 16, 0, 0)

// pack 2 f32 -> 1 u32 of 2 bf16 (RNE), elem0 = lo
#define CVTPK(dst, lo, hi) \
    asm("v_cvt_pk_bf16_f32 %0, %1, %2" : "=v"(dst) : "v"(lo), "v"(hi))

// a' = [a.lo | b.lo-of-partner], b' = [a.hi-of-partner | b.hi]
#define PLSWAP(a, b) \
    asm("v_permlane32_swap_b32 %0, %1" : "+v"(a), "+v"(b))

__device__ __forceinline__ ushort_t f2bu(float x) {
    unsigned u = __builtin_bit_cast(unsigned, x);
    unsigned r = (u + 0x7fffu + ((u >> 16) & 1u)) >> 16;   // RNE
    return (ushort_t)r;
}

// ---------------------------------------------------------------------------
// Fused prep: cvt_resid (blocks 0..4095) | tr_wqkv (4096..4607) |
//             tr_wout (4608..4863).  Whole-block branch, no divergence.
// ---------------------------------------------------------------------------
__global__ __launch_bounds__(256) void prep(
    const float* __restrict__ resid,
    const float* __restrict__ Wq, const float* __restrict__ Wk,
    const float* __restrict__ Wv, const float* __restrict__ Wout,
    ushort_t* __restrict__ rbf, ushort_t* __restrict__ Wt,
    ushort_t* __restrict__ Wot)
{
    __shared__ float Ws[64][65];
    const int t = threadIdx.x;
    const int bid = blockIdx.x;

    if (bid < 4096) {
        const int i4 = bid * 256 + t;
        union { float4 v; float f[4]; } a;
        a.v = *reinterpret_cast<const float4*>(resid + (size_t)i4 * 4);
        union { uint2 v; ushort_t u[4]; } o;
        #pragma unroll
        for (int j = 0; j < 4; ++j) o.u[j] = f2bu(a.f[j]);
        *reinterpret_cast<uint2*>(rbf + (size_t)i4 * 4) = o.v;
        return;
    }

    if (bid < 4096 + 512) {
        const int rel = bid - 4096;
        const int k0 = (rel & 15) * 64;
        const int n0 = (rel >> 4) * 64;

        const float* src; int stride, boff;
        if (n0 < 1024)       { src = Wq; stride = 1024; boff = n0; }
        else if (n0 < 1536)  { src = Wk; stride = 512;  boff = n0 - 1024; }
        else                 { src = Wv; stride = 512;  boff = n0 - 1536; }

        #pragma unroll
        for (int i = 0; i < 4; ++i) {
            const int c = i * 256 + t;
            const int row = c >> 4, cc = (c & 15) * 4;
            union { float4 v; float f[4]; } a;
            a.v = *reinterpret_cast<const float4*>(
                src + (size_t)(k0 + row) * stride + boff + cc);
            #pragma unroll
            for (int j = 0; j < 4; ++j) Ws[row][cc + j] = a.f[j];
        }
        __syncthreads();
        #pragma unroll
        for (int i = 0; i < 2; ++i) {
            const int c = i * 256 + t;
            const int nr = c >> 3, kc = (c & 7) * 8;
            union { uint4 v; ushort_t u[8]; } o;
            #pragma unroll
            for (int j = 0; j < 8; ++j) o.u[j] = f2bu(Ws[kc + j][nr]);
            *reinterpret_cast<uint4*>(Wt + (size_t)(n0 + nr) * 1024 + k0 + kc) = o.v;
        }
        return;
    }

    {
        const int rel = bid - 4608;
        const int d0 = (rel & 15) * 64;
        const int h  = rel >> 4;

        #pragma unroll
        for (int i = 0; i < 4; ++i) {
            const int c = i * 256 + t;
            const int e = c >> 4, dd = (c & 15) * 4;
            union { float4 v; float f[4]; } a;
            a.v = *reinterpret_cast<const float4*>(
                Wout + (size_t)(e * 16 + h) * 1024 + d0 + dd);
            #pragma unroll
            for (int j = 0; j < 4; ++j) Ws[e][dd + j] = a.f[j];
        }
        __syncthreads();
        #pragma unroll
        for (int i = 0; i < 2; ++i) {
            const int c = i * 256 + t;
            const int dr = c >> 3, ec = (c & 7) * 8;
            union { uint4 v; ushort_t u[8]; } o;
            #pragma unroll
            for (int j = 0; j < 8; ++j) o.u[j] = f2bu(Ws[ec + j][dr]);
            *reinterpret_cast<uint4*>(Wot + (size_t)(d0 + dr) * 1024 + h * 64 + ec) = o.v;
        }
    }
}

// ---------------------------------------------------------------------------
// Prep (after qkv_gemm): Vt[b][g][e][s] bf16 from qkv V slab.
// ---------------------------------------------------------------------------
__global__ __launch_bounds__(256) void tr_v(
    const ushort_t* __restrict__ qkv, ushort_t* __restrict__ Vt)
{
    __shared__ ushort_t T[64][72];
    const int t  = threadIdx.x;
    const int s0 = blockIdx.x * 64;
    const int g  = blockIdx.y;
    const int b  = blockIdx.z;

    #pragma unroll
    for (int i = 0; i < 2; ++i) {
        const int c = i * 256 + t;
        const int row = c >> 3, ec = (c & 7) * 8;
        *reinterpret_cast<uint4*>(&T[row][ec]) =
            *reinterpret_cast<const uint4*>(
                qkv + (size_t)(b * SEQ + s0 + row) * QKV_N + 1536 + g * 64 + ec);
    }
    __syncthreads();
    #pragma unroll
    for (int i = 0; i < 2; ++i) {
        const int c = i * 256 + t;
        const int er = c >> 3, sc = (c & 7) * 8;
        union { uint4 v; ushort_t u[8]; } o;
        #pragma unroll
        for (int j = 0; j < 8; ++j) o.u[j] = T[sc + j][er];
        *reinterpret_cast<uint4*>(
            Vt + (size_t)((b * NGROUPS + g) * 64 + er) * SEQ + s0 + sc) = o.v;
    }
}

// ---------------------------------------------------------------------------
// qkv_gemm (R6-measured-best, verbatim): 128x128 tile, BK=64, 512 THREADS
// (8 waves, 4x2 wave grid). 2 blocks/CU x 8 waves = 16 waves/CU.
// ---------------------------------------------------------------------------
__global__ __launch_bounds__(512) void qkv_gemm(
    const ushort_t* __restrict__ A, const ushort_t* __restrict__ Bt,
    ushort_t* __restrict__ C)
{
    __shared__ ushort_t As[128][64];
    __shared__ ushort_t Bs[128][64];

    const int t = threadIdx.x;
    const int wave = t >> 6, lane = t & 63;
    const int quad = lane >> 4, x = lane & 15;
    const int wm = (wave >> 1) * 32, wn = (wave & 1) * 64;
    const int m0 = blockIdx.y * 128, n0 = blockIdx.x * 128;

    const int sr8 = lane >> 3;                    // 0..7 rows per gload
    const int gc  = (lane & 7) ^ sr8;             // swizzled source chunk

    f32x4 acc[2][4];
    #pragma unroll
    for (int i = 0; i < 2; ++i)
        #pragma unroll
        for (int j = 0; j < 4; ++j) acc[i][j] = (f32x4)(0.f);

    for (int k0 = 0; k0 < 1024; k0 += 64) {
        #pragma unroll
        for (int s = 0; s < 2; ++s) {
            const int r0 = (wave * 2 + s) * 8;
            GLOAD16(A  + (size_t)(m0 + r0 + sr8) * 1024 + k0 + gc * 8, &As[r0][0]);
            GLOAD16(Bt + (size_t)(n0 + r0 + sr8) * 1024 + k0 + gc * 8, &Bs[r0][0]);
        }
        __syncthreads();
        #pragma unroll
        for (int j = 0; j < 2; ++j) {
            const int cs = ((j * 4 + quad) ^ (x & 7)) * 8;
            short8 af[2], bf[4];
            #pragma unroll
            for (int mt = 0; mt < 2; ++mt)
                af[mt] = *reinterpret_cast<const short8*>(&As[wm + mt * 16 + x][cs]);
            #pragma unroll
            for (int nt = 0; nt < 4; ++nt)
                bf[nt] = *reinterpret_cast<const short8*>(&Bs[wn + nt * 16 + x][cs]);
            #pragma unroll
            for (int mt = 0; mt < 2; ++mt)
                #pragma unroll
                for (int nt = 0; nt < 4; ++nt)
                    acc[mt][nt] = MFMA16(af[mt], bf[nt], acc[mt][nt]);
        }
        __syncthreads();
    }

    #pragma unroll
    for (int mt = 0; mt < 2; ++mt)
        #pragma unroll
        for (int nt = 0; nt < 4; ++nt)
            #pragma unroll
            for (int r = 0; r < 4; ++r) {
                const int row = m0 + wm + mt * 16 + quad * 4 + r;
                const int col = n0 + wn + nt * 16 + x;
                C[(size_t)row * QKV_N + col] = f2bu(acc[mt][nt][r]);
            }
}

// ---------------------------------------------------------------------------
// out_gemm (R6-measured-best, verbatim): 128x64 tile, BK=64, 512 threads.
// ---------------------------------------------------------------------------
__global__ __launch_bounds__(512) void out_gemm(
    const ushort_t* __restrict__ A, const ushort_t* __restrict__ Bt,
    const float* __restrict__ bias, float* __restrict__ C)
{
    __shared__ ushort_t As[128][64];
    __shared__ ushort_t Bs[64][64];

    const int t = threadIdx.x;
    const int wave = t >> 6, lane = t & 63;
    const int quad = lane >> 4, x = lane & 15;
    const int wm = (wave >> 1) * 32, wn = (wave & 1) * 32;
    const int m0 = blockIdx.y * 128, n0 = blockIdx.x * 64;

    const int sr8 = lane >> 3;
    const int gc  = (lane & 7) ^ sr8;

    f32x4 acc[2][2];
    #pragma unroll
    for (int i = 0; i < 2; ++i)
        #pragma unroll
        for (int j = 0; j < 2; ++j) acc[i][j] = (f32x4)(0.f);

    for (int k0 = 0; k0 < 1024; k0 += 64) {
        #pragma unroll
        for (int s = 0; s < 2; ++s) {
            const int r0 = (wave * 2 + s) * 8;
            GLOAD16(A + (size_t)(m0 + r0 + sr8) * 1024 + k0 + gc * 8, &As[r0][0]);
        }
        {
            const int r0 = wave * 8;
            GLOAD16(Bt + (size_t)(n0 + r0 + sr8) * 1024 + k0 + gc * 8, &Bs[r0][0]);
        }
        __syncthreads();
        #pragma unroll
        for (int j = 0; j < 2; ++j) {
            const int cs = ((j * 4 + quad) ^ (x & 7)) * 8;
            short8 af[2], bf[2];
            #pragma unroll
            for (int mt = 0; mt < 2; ++mt)
                af[mt] = *reinterpret_cast<const short8*>(&As[wm + mt * 16 + x][cs]);
            #pragma unroll
            for (int nt = 0; nt < 2; ++nt)
                bf[nt] = *reinterpret_cast<const short8*>(&Bs[wn + nt * 16 + x][cs]);
            #pragma unroll
            for (int mt = 0; mt < 2; ++mt)
                #pragma unroll
                for (int nt = 0; nt < 2; ++nt)
                    acc[mt][nt] = MFMA16(af[mt], bf[nt], acc[mt][nt]);
        }
        __syncthreads();
    }

    float bv[2];
    #pragma unroll
    for (int nt = 0; nt < 2; ++nt) bv[nt] = bias[n0 + wn + nt * 16 + x];

    #pragma unroll
    for (int mt = 0; mt < 2; ++mt)
        #pragma unroll
        for (int nt = 0; nt < 2; ++nt)
            #pragma unroll
            for (int r = 0; r < 4; ++r) {
                const int row = m0 + wm + mt * 16 + quad * 4 + r;
                const int col = n0 + wn + nt * 16 + x;
                C[(size_t)row * 1024 + col] = acc[mt][nt][r] + bv[nt];
            }
}

// ---------------------------------------------------------------------------
// MFMA flash attention, v10 (verified passing R7/R9/R10 — best at 44.5-46.8us):
//  32x32 MFMA + swapped QK^T + in-register P (CVTPK + permlane32_swap),
//  register-staged dbuf K/V, 8 waves rw x kw, paired q-tiles.
//  (v13 L2-direct: -30us regression, latency exposed; v14 reg-pipelined:
//   scratch-spill blowup. This LDS-staged form is the measured optimum.)
// ---------------------------------------------------------------------------
__global__ __launch_bounds__(512, 4) void attn(
    const ushort_t* __restrict__ qkv, const ushort_t* __restrict__ Vt,
    ushort_t* __restrict__ z)
{
    __shared__ ushort_t smem[4 * 128 * 64];   // Ks[2][128][64] | Vts[2][64][128]
    ushort_t (*Ks)[128][64]  = (ushort_t(*)[128][64])(smem);
    ushort_t (*Vts)[64][128] = (ushort_t(*)[64][128])(smem + 2 * 128 * 64);
    float* Ob1  = (float*)smem;                      // [64e][64q] over Ks[0]
    float* Ob3  = (float*)(smem + 128 * 64);         // over Ks[1]
    float* Ofin = (float*)(smem + 2 * 128 * 64);     // over Vts[0]
    float* Lb1  = (float*)(smem + 3 * 128 * 64);     // over Vts[1]
    float* Lb3  = Lb1 + 64;

    const int t = threadIdx.x;
    const int wave = t >> 6, lane = t & 63;
    const int x31 = lane & 31, hi = lane >> 5;
    const int rw = wave & 1;          // q 32-row half of the 64-row tile
    const int kw = wave >> 1;         // 32-key chunk of the 128-key tile

    const int h  = blockIdx.x;
    const int qp = blockIdx.y;
    const int b  = blockIdx.z;
    const int g  = h >> 1;

    // staging coords (512 threads stage K[128][64] + V^T[64][128] per tile)
    const int krow = t >> 3;          // rows krow, krow+64
    const int kc   = t & 7;
    const int vrow = t >> 4;          // rows vrow, vrow+32
    const int vc   = t & 15;

    const ushort_t* kgb = qkv + (size_t)(b * SEQ) * QKV_N + 1024 + g * 64 + kc * 8;
    const ushort_t* vgb = Vt + (size_t)((b * NGROUPS + g) * 64) * SEQ + vc * 8;

    const int kswz = (kc ^ (krow & 7)) * 8;
    const int vswz = (vc ^ (vrow & 15)) * 8;

    const int qloc = rw * 32 + x31;

    #pragma unroll
    for (int phase = 0; phase < 2; ++phase) {
        const int qt = phase ? (31 - qp) : qp;
        const int qrow0 = qt * 64;
        const int nkt = (qt >> 1) + 1;

        // ---- Q fragments (B-frag: lane holds Q[qloc][slice*16+hi*8 ..+7]) ----
        short8 aq[4];
        #pragma unroll
        for (int sl = 0; sl < 4; ++sl)
            aq[sl] = *reinterpret_cast<const short8*>(
                qkv + (size_t)(b * SEQ + qrow0 + qloc) * QKV_N + h * 64 + sl * 16 + hi * 8);

        f32x16 o0 = (f32x16)(0.f), o1 = (f32x16)(0.f);
        float lown = 0.f;

        __syncthreads();   // prev phase's Ofin reads done before staging writes

        // ---- prologue: stage tile 0 into buf0 ----
        {
            uint4 a0 = *reinterpret_cast<const uint4*>(kgb + (size_t)krow * QKV_N);
            uint4 a1 = *reinterpret_cast<const uint4*>(kgb + (size_t)(krow + 64) * QKV_N);
            uint4 b0 = *reinterpret_cast<const uint4*>(vgb + (size_t)vrow * SEQ);
            uint4 b1 = *reinterpret_cast<const uint4*>(vgb + (size_t)(vrow + 32) * SEQ);
            *reinterpret_cast<uint4*>(&Ks[0][krow][kswz])       = a0;
            *reinterpret_cast<uint4*>(&Ks[0][krow + 64][kswz])  = a1;
            *reinterpret_cast<uint4*>(&Vts[0][vrow][vswz])      = b0;
            *reinterpret_cast<uint4*>(&Vts[0][vrow + 32][vswz]) = b1;
        }
        __syncthreads();

        for (int kt = 0; kt < nkt; ++kt) {
            const int cur = kt & 1;
            const bool more = (kt + 1 < nkt);

            uint4 a0, a1, b0, b1;
            if (more) {
                const size_t kb = (size_t)((kt + 1) * 128);
                a0 = *reinterpret_cast<const uint4*>(kgb + (kb + krow) * QKV_N);
                a1 = *reinterpret_cast<const uint4*>(kgb + (kb + krow + 64) * QKV_N);
                b0 = *reinterpret_cast<const uint4*>(vgb + (size_t)vrow * SEQ + kb);
                b1 = *reinterpret_cast<const uint4*>(vgb + (size_t)(vrow + 32) * SEQ + kb);
            }

            const int cbase = kt * 128 + kw * 32;   // this wave's key chunk
            const int qmin  = qrow0 + rw * 32;

            if (cbase <= qmin + 31) {               // wave not fully masked
                const bool full = (cbase + 31 <= qmin);

                // --- S^T[32k x 32q] = K . Q^T over d=64 (4 slices) ---
                f32x16 st = (f32x16)(0.f);
                __builtin_amdgcn_s_setprio(1);
                #pragma unroll
                for (int sl = 0; sl < 4; ++sl) {
                    short8 ak = *reinterpret_cast<const short8*>(
                        &Ks[cur][kw * 32 + x31][((sl * 2 + hi) ^ (x31 & 7)) * 8]);
                    st = MFMA32(ak, aq[sl], st);
                }
                __builtin_amdgcn_s_setprio(0);

                // --- p = exp(s/8) (+causal mask), per-lane l partial ---
                const int ql = qmin + x31 - cbase;  // mask if keyoff > ql
                float p[16];
                float s16 = 0.f;
                #pragma unroll
                for (int r = 0; r < 16; ++r) {
                    const int keyoff = (r & 3) + 8 * (r >> 2);   // +4*hi
                    float pv = __expf(st[r] * 0.125f);
                    if (!full) pv = (keyoff + 4 * hi > ql) ? 0.f : pv;
                    p[r] = pv;
                    s16 += pv;
                }
                lown += s16;

                // --- pack to bf16, permlane into PV B-fragments ---
                u32 pk0, pk1, pk2, pk3, pk4, pk5, pk6, pk7;
                CVTPK(pk0, p[0],  p[1]);  CVTPK(pk1, p[2],  p[3]);
                CVTPK(pk2, p[4],  p[5]);  CVTPK(pk3, p[6],  p[7]);
                CVTPK(pk4, p[8],  p[9]);  CVTPK(pk5, p[10], p[11]);
                CVTPK(pk6, p[12], p[13]); CVTPK(pk7, p[14], p[15]);
                PLSWAP(pk0, pk2); PLSWAP(pk1, pk3);
                PLSWAP(pk4, pk6); PLSWAP(pk5, pk7);
                union { u32 u[4]; short8 s; } f0, f1;
                f0.u[0] = pk0; f0.u[1] = pk1; f0.u[2] = pk2; f0.u[3] = pk3;
                f1.u[0] = pk4; f1.u[1] = pk5; f1.u[2] = pk6; f1.u[3] = pk7;

                // --- O^T += V^T . P^T (2 e-tiles x 2 k-slices) ---
                __builtin_amdgcn_s_setprio(1);
                #pragma unroll
                for (int ks = 0; ks < 2; ++ks) {
                    const short8 pf = ks ? f1.s : f0.s;
                    short8 av0 = *reinterpret_cast<const short8*>(
                        &Vts[cur][x31][((kw * 4 + ks * 2 + hi) ^ (x31 & 15)) * 8]);
                    o0 = MFMA32(av0, pf, o0);
                    short8 av1 = *reinterpret_cast<const short8*>(
                        &Vts[cur][32 + x31][((kw * 4 + ks * 2 + hi) ^ (x31 & 15)) * 8]);
                    o1 = MFMA32(av1, pf, o1);
                }
                __builtin_amdgcn_s_setprio(0);
            }

            if (more) {
                *reinterpret_cast<uint4*>(&Ks[cur ^ 1][krow][kswz])       = a0;
                *reinterpret_cast<uint4*>(&Ks[cur ^ 1][krow + 64][kswz])  = a1;
                *reinterpret_cast<uint4*>(&Vts[cur ^ 1][vrow][vswz])      = b0;
                *reinterpret_cast<uint4*>(&Vts[cur ^ 1][vrow + 32][vswz]) = b1;
            }
            __syncthreads();
        }

        // ---- l: partner-exchange (lanes l <-> l+32 hold same q) ----
        float ltot;
        {
            u32 la = __builtin_bit_cast(u32, lown), lb = la;
            PLSWAP(la, lb);
            const float lpart = __builtin_bit_cast(float, hi ? la : lb);
            ltot = lown + lpart;
        }

        // ---- combine kw partials (tree via LDS overlays) ----
        if (kw == 1 || kw == 3) {
            float* Obx = (kw == 1) ? Ob1 : Ob3;
            float* Lbx = (kw == 1) ? Lb1 : Lb3;
            #pragma unroll
            for (int r = 0; r < 16; ++r) {
                const int e = (r & 3) + 8 * (r >> 2) + 4 * hi;
                Obx[e * 64 + qloc]        = o0[r];
                Obx[(32 + e) * 64 + qloc] = o1[r];
            }
            if (hi == 0) Lbx[qloc] = ltot;
        }
        __syncthreads();
        if (kw == 0 || kw == 2) {
            const float* Obx = (kw == 0) ? Ob1 : Ob3;
            const float* Lbx = (kw == 0) ? Lb1 : Lb3;
            #pragma unroll
            for (int r = 0; r < 16; ++r) {
                const int e = (r & 3) + 8 * (r >> 2) + 4 * hi;
                o0[r] += Obx[e * 64 + qloc];
                o1[r] += Obx[(32 + e) * 64 + qloc];
            }
            ltot += Lbx[qloc];
        }
        __syncthreads();
        if (kw == 2) {
            #pragma unroll
            for (int r = 0; r < 16; ++r) {
                const int e = (r & 3) + 8 * (r >> 2) + 4 * hi;
                Ob1[e * 64 + qloc]        = o0[r];
                Ob1[(32 + e) * 64 + qloc] = o1[r];
            }
            if (hi == 0) Lb1[qloc] = ltot;
        }
        __syncthreads();
        if (kw == 0) {
            #pragma unroll
            for (int r = 0; r < 16; ++r) {
                const int e = (r & 3) + 8 * (r >> 2) + 4 * hi;
                o0[r] += Ob1[e * 64 + qloc];
                o1[r] += Ob1[(32 + e) * 64 + qloc];
            }
            ltot += Lb1[qloc];
            const float inv = 1.f / ltot;
            #pragma unroll
            for (int r = 0; r < 16; ++r) {
                const int e = (r & 3) + 8 * (r >> 2) + 4 * hi;
                Ofin[e * 64 + qloc]        = o0[r] * inv;
                Ofin[(32 + e) * 64 + qloc] = o1[r] * inv;
            }
        }
        __syncthreads();

        // ---- z-write: coalesced 16B stores via LDS transpose ----
        {
            const int q = t >> 3, ec = t & 7;
            union { u32 u[4]; uint4 v; } pkz;
            #pragma unroll
            for (int j2 = 0; j2 < 4; ++j2) {
                float v0 = Ofin[(ec * 8 + 2 * j2) * 64 + q];
                float v1 = Ofin[(ec * 8 + 2 * j2 + 1) * 64 + q];
                CVTPK(pkz.u[j2], v0, v1);
            }
            *reinterpret_cast<uint4*>(
                z + (size_t)(b * SEQ + qrow0 + q) * 1024 + h * 64 + ec * 8) = pkz.v;
        }
    }
}

// ---------------------------------------------------------------------------
extern "C" void kernel_launch(void* const* d_in, const int* in_sizes, int n_in,
                              void* d_out, int out_size, void* d_ws, size_t ws_size,
                              hipStream_t stream)
{
    const float* resid = (const float*)d_in[0];
    const float* Wq    = (const float*)d_in[1];
    const float* Wk    = (const float*)d_in[2];
    const float* Wv    = (const float*)d_in[3];
    const float* Wout  = (const float*)d_in[4];
    const float* bout  = (const float*)d_in[5];
    float* out = (float*)d_out;

    ushort_t* rbf   = (ushort_t*)d_ws;                       //  8 MB  [4096][1024]
    ushort_t* wqkvt = rbf   + (size_t)NTOK * DMODEL;         //  4 MB  [2048][1024]
    ushort_t* woutt = wqkvt + (size_t)QKV_N * DMODEL;        //  2 MB  [1024][1024]
    ushort_t* qkv   = woutt + (size_t)DMODEL * DMODEL;       // 16 MB  [4096][2048]
    ushort_t* z     = qkv   + (size_t)NTOK * QKV_N;          //  8 MB  [4096][1024]
    ushort_t* vt    = rbf;   // alias: rbf dead after qkv_gemm; tr_v runs later

    prep     <<<dim3(4864), 256, 0, stream>>>(resid, Wq, Wk, Wv, Wout,
                                              rbf, wqkvt, woutt);
    qkv_gemm <<<dim3(16, 32), 512, 0, stream>>>(rbf, wqkvt, qkv);
    tr_v     <<<dim3(SEQ / 64, NGROUPS, BATCH), 256, 0, stream>>>(qkv, vt);
    attn     <<<dim3(16, 16, 2), 512, 0, stream>>>(qkv, vt, z);
    out_gemm <<<dim3(16, 32), 512, 0, stream>>>(z, woutt, bout, out);
}

// Round 14
// 162.354 us; speedup vs baseline: 1.3575x; 1.0122x over previous
//
#include <hip/hip_runtime.h>

#define BATCH   2
#define SEQ     2048
#define DMODEL  1024
#define NHEADS  16
#define DHEAD   64
#define NGROUPS 8
#define NTOK    (BATCH * SEQ)   // 4096
#define QKV_N   2048            // 1024 Q | 512 K | 512 V

typedef unsigned short ushort_t;
typedef unsigned int u32;
typedef __attribute__((ext_vector_type(8))) short short8;
typedef __attribute__((ext_vector_type(4))) float f32x4;
typedef __attribute__((ext_vector_type(16))) float f32x16;

#define MFMA16(a, b, c) __builtin_amdgcn_mfma_f32_16x16x32_bf16((a), (b), (c), 0, 0, 0)
#define MFMA32(a, b, c) __builtin_amdgcn_mfma_f32_32x32x16_bf16((a), (b), (c), 0, 0, 0)

// async global->LDS, 16B per lane, LDS dest = wave-uniform base + lane*16
#define GLOAD16(gp, lp)                                                        \
    __builtin_amdgcn_global_load_lds(                                          \
        (const u32 __attribute__((address_space(1)))*)(gp),                    \
        (u32 __attribute__((address_space(3)))*)(lp), 16, 0, 0)

// pack 2 f32 -> 1 u32 of 2 bf16 (RNE), elem0 = lo
#define CVTPK(dst, lo, hi) \
    asm("v_cvt_pk_bf16_f32 %0, %1, %2" : "=v"(dst) : "v"(lo), "v"(hi))

// a' = [a.lo | b.lo-of-partner], b' = [a.hi-of-partner | b.hi]
#define PLSWAP(a, b) \
    asm("v_permlane32_swap_b32 %0, %1" : "+v"(a), "+v"(b))

__device__ __forceinline__ ushort_t f2bu(float x) {
    unsigned u = __builtin_bit_cast(unsigned, x);
    unsigned r = (u + 0x7fffu + ((u >> 16) & 1u)) >> 16;   // RNE
    return (ushort_t)r;
}

// ---------------------------------------------------------------------------
// Fused prep: cvt_resid (blocks 0..4095) | tr_wqkv (4096..4607) |
//             tr_wout (4608..4863).  Whole-block branch, no divergence.
// ---------------------------------------------------------------------------
__global__ __launch_bounds__(256) void prep(
    const float* __restrict__ resid,
    const float* __restrict__ Wq, const float* __restrict__ Wk,
    const float* __restrict__ Wv, const float* __restrict__ Wout,
    ushort_t* __restrict__ rbf, ushort_t* __restrict__ Wt,
    ushort_t* __restrict__ Wot)
{
    __shared__ float Ws[64][65];
    const int t = threadIdx.x;
    const int bid = blockIdx.x;

    if (bid < 4096) {
        const int i4 = bid * 256 + t;
        union { float4 v; float f[4]; } a;
        a.v = *reinterpret_cast<const float4*>(resid + (size_t)i4 * 4);
        union { uint2 v; ushort_t u[4]; } o;
        #pragma unroll
        for (int j = 0; j < 4; ++j) o.u[j] = f2bu(a.f[j]);
        *reinterpret_cast<uint2*>(rbf + (size_t)i4 * 4) = o.v;
        return;
    }

    if (bid < 4096 + 512) {
        const int rel = bid - 4096;
        const int k0 = (rel & 15) * 64;
        const int n0 = (rel >> 4) * 64;

        const float* src; int stride, boff;
        if (n0 < 1024)       { src = Wq; stride = 1024; boff = n0; }
        else if (n0 < 1536)  { src = Wk; stride = 512;  boff = n0 - 1024; }
        else                 { src = Wv; stride = 512;  boff = n0 - 1536; }

        #pragma unroll
        for (int i = 0; i < 4; ++i) {
            const int c = i * 256 + t;
            const int row = c >> 4, cc = (c & 15) * 4;
            union { float4 v; float f[4]; } a;
            a.v = *reinterpret_cast<const float4*>(
                src + (size_t)(k0 + row) * stride + boff + cc);
            #pragma unroll
            for (int j = 0; j < 4; ++j) Ws[row][cc + j] = a.f[j];
        }
        __syncthreads();
        #pragma unroll
        for (int i = 0; i < 2; ++i) {
            const int c = i * 256 + t;
            const int nr = c >> 3, kc = (c & 7) * 8;
            union { uint4 v; ushort_t u[8]; } o;
            #pragma unroll
            for (int j = 0; j < 8; ++j) o.u[j] = f2bu(Ws[kc + j][nr]);
            *reinterpret_cast<uint4*>(Wt + (size_t)(n0 + nr) * 1024 + k0 + kc) = o.v;
        }
        return;
    }

    {
        const int rel = bid - 4608;
        const int d0 = (rel & 15) * 64;
        const int h  = rel >> 4;

        #pragma unroll
        for (int i = 0; i < 4; ++i) {
            const int c = i * 256 + t;
            const int e = c >> 4, dd = (c & 15) * 4;
            union { float4 v; float f[4]; } a;
            a.v = *reinterpret_cast<const float4*>(
                Wout + (size_t)(e * 16 + h) * 1024 + d0 + dd);
            #pragma unroll
            for (int j = 0; j < 4; ++j) Ws[e][dd + j] = a.f[j];
        }
        __syncthreads();
        #pragma unroll
        for (int i = 0; i < 2; ++i) {
            const int c = i * 256 + t;
            const int dr = c >> 3, ec = (c & 7) * 8;
            union { uint4 v; ushort_t u[8]; } o;
            #pragma unroll
            for (int j = 0; j < 8; ++j) o.u[j] = f2bu(Ws[ec + j][dr]);
            *reinterpret_cast<uint4*>(Wot + (size_t)(d0 + dr) * 1024 + h * 64 + ec) = o.v;
        }
    }
}

// ---------------------------------------------------------------------------
// tr_v (fallback only, when workspace too small for fused V^T):
// Vt[b][g][e][s] bf16 from qkv V slab.
// ---------------------------------------------------------------------------
__global__ __launch_bounds__(256) void tr_v(
    const ushort_t* __restrict__ qkv, ushort_t* __restrict__ Vt)
{
    __shared__ ushort_t T[64][72];
    const int t  = threadIdx.x;
    const int s0 = blockIdx.x * 64;
    const int g  = blockIdx.y;
    const int b  = blockIdx.z;

    #pragma unroll
    for (int i = 0; i < 2; ++i) {
        const int c = i * 256 + t;
        const int row = c >> 3, ec = (c & 7) * 8;
        *reinterpret_cast<uint4*>(&T[row][ec]) =
            *reinterpret_cast<const uint4*>(
                qkv + (size_t)(b * SEQ + s0 + row) * QKV_N + 1536 + g * 64 + ec);
    }
    __syncthreads();
    #pragma unroll
    for (int i = 0; i < 2; ++i) {
        const int c = i * 256 + t;
        const int er = c >> 3, sc = (c & 7) * 8;
        union { uint4 v; ushort_t u[8]; } o;
        #pragma unroll
        for (int j = 0; j < 8; ++j) o.u[j] = T[sc + j][er];
        *reinterpret_cast<uint4*>(
            Vt + (size_t)((b * NGROUPS + g) * 64 + er) * SEQ + s0 + sc) = o.v;
    }
}

// ---------------------------------------------------------------------------
// qkv_gemm (R6 loop verbatim) + FUSED V^T EPILOGUE:
// blocks with n0>=1536 hold exactly the V slab in their accumulators; when
// fuse_v!=0 they write Vt[(b*512+v)*SEQ+s] directly (4 tokens = one uint2,
// contiguous in s — identical bits to the old qkv->tr_v round trip) and
// skip the now-dead qkv C-write. Saves the tr_v dispatch + 8MB traffic.
// ---------------------------------------------------------------------------
__global__ __launch_bounds__(512) void qkv_gemm(
    const ushort_t* __restrict__ A, const ushort_t* __restrict__ Bt,
    ushort_t* __restrict__ C, ushort_t* __restrict__ Vt, int fuse_v)
{
    __shared__ ushort_t As[128][64];
    __shared__ ushort_t Bs[128][64];

    const int t = threadIdx.x;
    const int wave = t >> 6, lane = t & 63;
    const int quad = lane >> 4, x = lane & 15;
    const int wm = (wave >> 1) * 32, wn = (wave & 1) * 64;
    const int m0 = blockIdx.y * 128, n0 = blockIdx.x * 128;

    const int sr8 = lane >> 3;                    // 0..7 rows per gload
    const int gc  = (lane & 7) ^ sr8;             // swizzled source chunk

    f32x4 acc[2][4];
    #pragma unroll
    for (int i = 0; i < 2; ++i)
        #pragma unroll
        for (int j = 0; j < 4; ++j) acc[i][j] = (f32x4)(0.f);

    for (int k0 = 0; k0 < 1024; k0 += 64) {
        #pragma unroll
        for (int s = 0; s < 2; ++s) {
            const int r0 = (wave * 2 + s) * 8;
            GLOAD16(A  + (size_t)(m0 + r0 + sr8) * 1024 + k0 + gc * 8, &As[r0][0]);
            GLOAD16(Bt + (size_t)(n0 + r0 + sr8) * 1024 + k0 + gc * 8, &Bs[r0][0]);
        }
        __syncthreads();
        #pragma unroll
        for (int j = 0; j < 2; ++j) {
            const int cs = ((j * 4 + quad) ^ (x & 7)) * 8;
            short8 af[2], bf[4];
            #pragma unroll
            for (int mt = 0; mt < 2; ++mt)
                af[mt] = *reinterpret_cast<const short8*>(&As[wm + mt * 16 + x][cs]);
            #pragma unroll
            for (int nt = 0; nt < 4; ++nt)
                bf[nt] = *reinterpret_cast<const short8*>(&Bs[wn + nt * 16 + x][cs]);
            #pragma unroll
            for (int mt = 0; mt < 2; ++mt)
                #pragma unroll
                for (int nt = 0; nt < 4; ++nt)
                    acc[mt][nt] = MFMA16(af[mt], bf[nt], acc[mt][nt]);
        }
        __syncthreads();
    }

    if (fuse_v && n0 >= 1536) {
        // V^T epilogue: acc[mt][nt][r] = V[s+r][v];  Vt[(b*512+v)][s..s+3]
        const int bb = m0 >> 11;                    // token-block batch
        const int sb = (m0 & 2047) + wm;            // token base within batch
        #pragma unroll
        for (int mt = 0; mt < 2; ++mt)
            #pragma unroll
            for (int nt = 0; nt < 4; ++nt) {
                const int v  = (n0 - 1536) + wn + nt * 16 + x;   // g*64+e
                const int ss = sb + mt * 16 + quad * 4;
                union { uint2 u; ushort_t us[4]; } pk;
                #pragma unroll
                for (int r = 0; r < 4; ++r) pk.us[r] = f2bu(acc[mt][nt][r]);
                *reinterpret_cast<uint2*>(
                    Vt + ((size_t)bb * 512 + v) * SEQ + ss) = pk.u;
            }
    } else {
        #pragma unroll
        for (int mt = 0; mt < 2; ++mt)
            #pragma unroll
            for (int nt = 0; nt < 4; ++nt)
                #pragma unroll
                for (int r = 0; r < 4; ++r) {
                    const int row = m0 + wm + mt * 16 + quad * 4 + r;
                    const int col = n0 + wn + nt * 16 + x;
                    C[(size_t)row * QKV_N + col] = f2bu(acc[mt][nt][r]);
                }
    }
}

// ---------------------------------------------------------------------------
// out_gemm (R6-measured-best, verbatim): 128x64 tile, BK=64, 512 threads.
// ---------------------------------------------------------------------------
__global__ __launch_bounds__(512) void out_gemm(
    const ushort_t* __restrict__ A, const ushort_t* __restrict__ Bt,
    const float* __restrict__ bias, float* __restrict__ C)
{
    __shared__ ushort_t As[128][64];
    __shared__ ushort_t Bs[64][64];

    const int t = threadIdx.x;
    const int wave = t >> 6, lane = t & 63;
    const int quad = lane >> 4, x = lane & 15;
    const int wm = (wave >> 1) * 32, wn = (wave & 1) * 32;
    const int m0 = blockIdx.y * 128, n0 = blockIdx.x * 64;

    const int sr8 = lane >> 3;
    const int gc  = (lane & 7) ^ sr8;

    f32x4 acc[2][2];
    #pragma unroll
    for (int i = 0; i < 2; ++i)
        #pragma unroll
        for (int j = 0; j < 2; ++j) acc[i][j] = (f32x4)(0.f);

    for (int k0 = 0; k0 < 1024; k0 += 64) {
        #pragma unroll
        for (int s = 0; s < 2; ++s) {
            const int r0 = (wave * 2 + s) * 8;
            GLOAD16(A + (size_t)(m0 + r0 + sr8) * 1024 + k0 + gc * 8, &As[r0][0]);
        }
        {
            const int r0 = wave * 8;
            GLOAD16(Bt + (size_t)(n0 + r0 + sr8) * 1024 + k0 + gc * 8, &Bs[r0][0]);
        }
        __syncthreads();
        #pragma unroll
        for (int j = 0; j < 2; ++j) {
            const int cs = ((j * 4 + quad) ^ (x & 7)) * 8;
            short8 af[2], bf[2];
            #pragma unroll
            for (int mt = 0; mt < 2; ++mt)
                af[mt] = *reinterpret_cast<const short8*>(&As[wm + mt * 16 + x][cs]);
            #pragma unroll
            for (int nt = 0; nt < 2; ++nt)
                bf[nt] = *reinterpret_cast<const short8*>(&Bs[wn + nt * 16 + x][cs]);
            #pragma unroll
            for (int mt = 0; mt < 2; ++mt)
                #pragma unroll
                for (int nt = 0; nt < 2; ++nt)
                    acc[mt][nt] = MFMA16(af[mt], bf[nt], acc[mt][nt]);
        }
        __syncthreads();
    }

    float bv[2];
    #pragma unroll
    for (int nt = 0; nt < 2; ++nt) bv[nt] = bias[n0 + wn + nt * 16 + x];

    #pragma unroll
    for (int mt = 0; mt < 2; ++mt)
        #pragma unroll
        for (int nt = 0; nt < 2; ++nt)
            #pragma unroll
            for (int r = 0; r < 4; ++r) {
                const int row = m0 + wm + mt * 16 + quad * 4 + r;
                const int col = n0 + wn + nt * 16 + x;
                C[(size_t)row * 1024 + col] = acc[mt][nt][r] + bv[nt];
            }
}

// ---------------------------------------------------------------------------
// MFMA flash attention, v10 (verified passing R7/R9/R10/R13 — 44.2-46.8us):
//  32x32 MFMA + swapped QK^T + in-register P (CVTPK + permlane32_swap),
//  register-staged dbuf K/V, 8 waves rw x kw, paired q-tiles.
// ---------------------------------------------------------------------------
__global__ __launch_bounds__(512, 4) void attn(
    const ushort_t* __restrict__ qkv, const ushort_t* __restrict__ Vt,
    ushort_t* __restrict__ z)
{
    __shared__ ushort_t smem[4 * 128 * 64];   // Ks[2][128][64] | Vts[2][64][128]
    ushort_t (*Ks)[128][64]  = (ushort_t(*)[128][64])(smem);
    ushort_t (*Vts)[64][128] = (ushort_t(*)[64][128])(smem + 2 * 128 * 64);
    float* Ob1  = (float*)smem;                      // [64e][64q] over Ks[0]
    float* Ob3  = (float*)(smem + 128 * 64);         // over Ks[1]
    float* Ofin = (float*)(smem + 2 * 128 * 64);     // over Vts[0]
    float* Lb1  = (float*)(smem + 3 * 128 * 64);     // over Vts[1]
    float* Lb3  = Lb1 + 64;

    const int t = threadIdx.x;
    const int wave = t >> 6, lane = t & 63;
    const int x31 = lane & 31, hi = lane >> 5;
    const int rw = wave & 1;          // q 32-row half of the 64-row tile
    const int kw = wave >> 1;         // 32-key chunk of the 128-key tile

    const int h  = blockIdx.x;
    const int qp = blockIdx.y;
    const int b  = blockIdx.z;
    const int g  = h >> 1;

    // staging coords (512 threads stage K[128][64] + V^T[64][128] per tile)
    const int krow = t >> 3;          // rows krow, krow+64
    const int kc   = t & 7;
    const int vrow = t >> 4;          // rows vrow, vrow+32
    const int vc   = t & 15;

    const ushort_t* kgb = qkv + (size_t)(b * SEQ) * QKV_N + 1024 + g * 64 + kc * 8;
    const ushort_t* vgb = Vt + (size_t)((b * NGROUPS + g) * 64) * SEQ + vc * 8;

    const int kswz = (kc ^ (krow & 7)) * 8;
    const int vswz = (vc ^ (vrow & 15)) * 8;

    const int qloc = rw * 32 + x31;

    #pragma unroll
    for (int phase = 0; phase < 2; ++phase) {
        const int qt = phase ? (31 - qp) : qp;
        const int qrow0 = qt * 64;
        const int nkt = (qt >> 1) + 1;

        // ---- Q fragments (B-frag: lane holds Q[qloc][slice*16+hi*8 ..+7]) ----
        short8 aq[4];
        #pragma unroll
        for (int sl = 0; sl < 4; ++sl)
            aq[sl] = *reinterpret_cast<const short8*>(
                qkv + (size_t)(b * SEQ + qrow0 + qloc) * QKV_N + h * 64 + sl * 16 + hi * 8);

        f32x16 o0 = (f32x16)(0.f), o1 = (f32x16)(0.f);
        float lown = 0.f;

        __syncthreads();   // prev phase's Ofin reads done before staging writes

        // ---- prologue: stage tile 0 into buf0 ----
        {
            uint4 a0 = *reinterpret_cast<const uint4*>(kgb + (size_t)krow * QKV_N);
            uint4 a1 = *reinterpret_cast<const uint4*>(kgb + (size_t)(krow + 64) * QKV_N);
            uint4 b0 = *reinterpret_cast<const uint4*>(vgb + (size_t)vrow * SEQ);
            uint4 b1 = *reinterpret_cast<const uint4*>(vgb + (size_t)(vrow + 32) * SEQ);
            *reinterpret_cast<uint4*>(&Ks[0][krow][kswz])       = a0;
            *reinterpret_cast<uint4*>(&Ks[0][krow + 64][kswz])  = a1;
            *reinterpret_cast<uint4*>(&Vts[0][vrow][vswz])      = b0;
            *reinterpret_cast<uint4*>(&Vts[0][vrow + 32][vswz]) = b1;
        }
        __syncthreads();

        for (int kt = 0; kt < nkt; ++kt) {
            const int cur = kt & 1;
            const bool more = (kt + 1 < nkt);

            uint4 a0, a1, b0, b1;
            if (more) {
                const size_t kb = (size_t)((kt + 1) * 128);
                a0 = *reinterpret_cast<const uint4*>(kgb + (kb + krow) * QKV_N);
                a1 = *reinterpret_cast<const uint4*>(kgb + (kb + krow + 64) * QKV_N);
                b0 = *reinterpret_cast<const uint4*>(vgb + (size_t)vrow * SEQ + kb);
                b1 = *reinterpret_cast<const uint4*>(vgb + (size_t)(vrow + 32) * SEQ + kb);
            }

            const int cbase = kt * 128 + kw * 32;   // this wave's key chunk
            const int qmin  = qrow0 + rw * 32;

            if (cbase <= qmin + 31) {               // wave not fully masked
                const bool full = (cbase + 31 <= qmin);

                // --- S^T[32k x 32q] = K . Q^T over d=64 (4 slices) ---
                f32x16 st = (f32x16)(0.f);
                __builtin_amdgcn_s_setprio(1);
                #pragma unroll
                for (int sl = 0; sl < 4; ++sl) {
                    short8 ak = *reinterpret_cast<const short8*>(
                        &Ks[cur][kw * 32 + x31][((sl * 2 + hi) ^ (x31 & 7)) * 8]);
                    st = MFMA32(ak, aq[sl], st);
                }
                __builtin_amdgcn_s_setprio(0);

                // --- p = exp(s/8) (+causal mask), per-lane l partial ---
                const int ql = qmin + x31 - cbase;  // mask if keyoff > ql
                float p[16];
                float s16 = 0.f;
                #pragma unroll
                for (int r = 0; r < 16; ++r) {
                    const int keyoff = (r & 3) + 8 * (r >> 2);   // +4*hi
                    float pv = __expf(st[r] * 0.125f);
                    if (!full) pv = (keyoff + 4 * hi > ql) ? 0.f : pv;
                    p[r] = pv;
                    s16 += pv;
                }
                lown += s16;

                // --- pack to bf16, permlane into PV B-fragments ---
                u32 pk0, pk1, pk2, pk3, pk4, pk5, pk6, pk7;
                CVTPK(pk0, p[0],  p[1]);  CVTPK(pk1, p[2],  p[3]);
                CVTPK(pk2, p[4],  p[5]);  CVTPK(pk3, p[6],  p[7]);
                CVTPK(pk4, p[8],  p[9]);  CVTPK(pk5, p[10], p[11]);
                CVTPK(pk6, p[12], p[13]); CVTPK(pk7, p[14], p[15]);
                PLSWAP(pk0, pk2); PLSWAP(pk1, pk3);
                PLSWAP(pk4, pk6); PLSWAP(pk5, pk7);
                union { u32 u[4]; short8 s; } f0, f1;
                f0.u[0] = pk0; f0.u[1] = pk1; f0.u[2] = pk2; f0.u[3] = pk3;
                f1.u[0] = pk4; f1.u[1] = pk5; f1.u[2] = pk6; f1.u[3] = pk7;

                // --- O^T += V^T . P^T (2 e-tiles x 2 k-slices) ---
                __builtin_amdgcn_s_setprio(1);
                #pragma unroll
                for (int ks = 0; ks < 2; ++ks) {
                    const short8 pf = ks ? f1.s : f0.s;
                    short8 av0 = *reinterpret_cast<const short8*>(
                        &Vts[cur][x31][((kw * 4 + ks * 2 + hi) ^ (x31 & 15)) * 8]);
                    o0 = MFMA32(av0, pf, o0);
                    short8 av1 = *reinterpret_cast<const short8*>(
                        &Vts[cur][32 + x31][((kw * 4 + ks * 2 + hi) ^ (x31 & 15)) * 8]);
                    o1 = MFMA32(av1, pf, o1);
                }
                __builtin_amdgcn_s_setprio(0);
            }

            if (more) {
                *reinterpret_cast<uint4*>(&Ks[cur ^ 1][krow][kswz])       = a0;
                *reinterpret_cast<uint4*>(&Ks[cur ^ 1][krow + 64][kswz])  = a1;
                *reinterpret_cast<uint4*>(&Vts[cur ^ 1][vrow][vswz])      = b0;
                *reinterpret_cast<uint4*>(&Vts[cur ^ 1][vrow + 32][vswz]) = b1;
            }
            __syncthreads();
        }

        // ---- l: partner-exchange (lanes l <-> l+32 hold same q) ----
        float ltot;
        {
            u32 la = __builtin_bit_cast(u32, lown), lb = la;
            PLSWAP(la, lb);
            const float lpart = __builtin_bit_cast(float, hi ? la : lb);
            ltot = lown + lpart;
        }

        // ---- combine kw partials (tree via LDS overlays) ----
        if (kw == 1 || kw == 3) {
            float* Obx = (kw == 1) ? Ob1 : Ob3;
            float* Lbx = (kw == 1) ? Lb1 : Lb3;
            #pragma unroll
            for (int r = 0; r < 16; ++r) {
                const int e = (r & 3) + 8 * (r >> 2) + 4 * hi;
                Obx[e * 64 + qloc]        = o0[r];
                Obx[(32 + e) * 64 + qloc] = o1[r];
            }
            if (hi == 0) Lbx[qloc] = ltot;
        }
        __syncthreads();
        if (kw == 0 || kw == 2) {
            const float* Obx = (kw == 0) ? Ob1 : Ob3;
            const float* Lbx = (kw == 0) ? Lb1 : Lb3;
            #pragma unroll
            for (int r = 0; r < 16; ++r) {
                const int e = (r & 3) + 8 * (r >> 2) + 4 * hi;
                o0[r] += Obx[e * 64 + qloc];
                o1[r] += Obx[(32 + e) * 64 + qloc];
            }
            ltot += Lbx[qloc];
        }
        __syncthreads();
        if (kw == 2) {
            #pragma unroll
            for (int r = 0; r < 16; ++r) {
                const int e = (r & 3) + 8 * (r >> 2) + 4 * hi;
                Ob1[e * 64 + qloc]        = o0[r];
                Ob1[(32 + e) * 64 + qloc] = o1[r];
            }
            if (hi == 0) Lb1[qloc] = ltot;
        }
        __syncthreads();
        if (kw == 0) {
            #pragma unroll
            for (int r = 0; r < 16; ++r) {
                const int e = (r & 3) + 8 * (r >> 2) + 4 * hi;
                o0[r] += Ob1[e * 64 + qloc];
                o1[r] += Ob1[(32 + e) * 64 + qloc];
            }
            ltot += Lb1[qloc];
            const float inv = 1.f / ltot;
            #pragma unroll
            for (int r = 0; r < 16; ++r) {
                const int e = (r & 3) + 8 * (r >> 2) + 4 * hi;
                Ofin[e * 64 + qloc]        = o0[r] * inv;
                Ofin[(32 + e) * 64 + qloc] = o1[r] * inv;
            }
        }
        __syncthreads();

        // ---- z-write: coalesced 16B stores via LDS transpose ----
        {
            const int q = t >> 3, ec = t & 7;
            union { u32 u[4]; uint4 v; } pkz;
            #pragma unroll
            for (int j2 = 0; j2 < 4; ++j2) {
                float v0 = Ofin[(ec * 8 + 2 * j2) * 64 + q];
                float v1 = Ofin[(ec * 8 + 2 * j2 + 1) * 64 + q];
                CVTPK(pkz.u[j2], v0, v1);
            }
            *reinterpret_cast<uint4*>(
                z + (size_t)(b * SEQ + qrow0 + q) * 1024 + h * 64 + ec * 8) = pkz.v;
        }
    }
}

// ---------------------------------------------------------------------------
extern "C" void kernel_launch(void* const* d_in, const int* in_sizes, int n_in,
                              void* d_out, int out_size, void* d_ws, size_t ws_size,
                              hipStream_t stream)
{
    const float* resid = (const float*)d_in[0];
    const float* Wq    = (const float*)d_in[1];
    const float* Wk    = (const float*)d_in[2];
    const float* Wv    = (const float*)d_in[3];
    const float* Wout  = (const float*)d_in[4];
    const float* bout  = (const float*)d_in[5];
    float* out = (float*)d_out;

    ushort_t* rbf   = (ushort_t*)d_ws;                       //  8 MB  [4096][1024]
    ushort_t* wqkvt = rbf   + (size_t)NTOK * DMODEL;         //  4 MB  [2048][1024]
    ushort_t* woutt = wqkvt + (size_t)QKV_N * DMODEL;        //  2 MB  [1024][1024]
    ushort_t* qkv   = woutt + (size_t)DMODEL * DMODEL;       // 16 MB  [4096][2048]
    ushort_t* z     = qkv   + (size_t)NTOK * QKV_N;          //  8 MB  [4096][1024]

    // Fused V^T needs a Vt buffer DISJOINT from rbf (qkv_gemm reads rbf as A
    // while writing Vt). 38MB base + 4MB Vt = 42MB. Capture-time-constant
    // branch on ws_size -> graph-safe; fallback = R13-identical behavior.
    const size_t need = ((size_t)38 << 20) + ((size_t)4 << 20);
    const bool fuse = (ws_size >= need);
    ushort_t* vt = fuse ? (z + (size_t)NTOK * DMODEL)        //  4 MB  [2][8][64][2048]
                        : rbf;                               //  alias (fallback)

    prep     <<<dim3(4864), 256, 0, stream>>>(resid, Wq, Wk, Wv, Wout,
                                              rbf, wqkvt, woutt);
    qkv_gemm <<<dim3(16, 32), 512, 0, stream>>>(rbf, wqkvt, qkv, vt, fuse ? 1 : 0);
    if (!fuse)
        tr_v <<<dim3(SEQ / 64, NGROUPS, BATCH), 256, 0, stream>>>(qkv, vt);
    attn     <<<dim3(16, 16, 2), 512, 0, stream>>>(qkv, vt, z);
    out_gemm <<<dim3(16, 32), 512, 0, stream>>>(z, woutt, bout, out);
}